// Round 1
// baseline (1916.014 us; speedup 1.0000x reference)
//
#include <hip/hip_runtime.h>
#include <math.h>

typedef float f4 __attribute__((ext_vector_type(4)));

// Problem constants
#define NBATCH 4096
#define NAGENT 64
#define OBSIN  128
#define DDIM   64
#define NACT   16

// ws layout (float offsets): pre-transposed weights (K-major for B-operand reads)
#define WS_EMBT 0        // [128][64]  WembT[f][h] = W_emb[h][f]
#define WS_KT   8192     // [64][64]   WkT[h][d]   = W_k[d][h]
#define WS_QT   12288    // [64][64]
#define WS_VT   16384    // [64][64]
#define WS_F1T  20480    // [64][64]   Wf1T[d][hh] = W_f1[hh][d]
#define WS_F2T  24576    // [64][16]   Wf2T[hh][a] = W_f2[a][hh]
#define WS_TOTAL 25600

__global__ void transpose_weights_kernel(const float* __restrict__ W_emb,
                                         const float* __restrict__ W_k,
                                         const float* __restrict__ W_q,
                                         const float* __restrict__ W_v,
                                         const float* __restrict__ W_f1,
                                         const float* __restrict__ W_f2,
                                         float* __restrict__ ws) {
  int idx = blockIdx.x * 256 + threadIdx.x;
  if (idx >= WS_TOTAL) return;
  float v;
  if (idx < 8192)       { int f = idx >> 6,          h = idx & 63;          v = W_emb[h * 128 + f]; }
  else if (idx < 12288) { int r = idx - 8192;  int h = r >> 6, d = r & 63;  v = W_k[d * 64 + h]; }
  else if (idx < 16384) { int r = idx - 12288; int h = r >> 6, d = r & 63;  v = W_q[d * 64 + h]; }
  else if (idx < 20480) { int r = idx - 16384; int h = r >> 6, d = r & 63;  v = W_v[d * 64 + h]; }
  else if (idx < 24576) { int r = idx - 20480; int d = r >> 6, hh = r & 63; v = W_f1[hh * 64 + d]; }
  else                  { int r = idx - 24576; int hh = r >> 4, a = r & 15; v = W_f2[a * 64 + hh]; }
  ws[idx] = v;
}

// XOR swizzle for A-type (row-major, rows read as scalar-broadcast/b128 column-chunks).
// word(r,c) = r*64 + (c ^ ((r&7)<<2)); keeps 16B alignment (xor is a multiple of 4).
__device__ __forceinline__ int swz(int r, int c) { return r * 64 + (c ^ ((r & 7) << 2)); }

// ---- 4x4-tile matmul helpers (64x64 output, 16x16 thread grid) ----
// A: LDS row-major swizzled; B: row-major K-major, plain addressing (LDS or global)
template <int K>
__device__ __forceinline__ void mm_Aswz_Bplain(const float* __restrict__ sA,
                                               const float* __restrict__ Bp,
                                               int tm, int tn, float acc[4][4]) {
  for (int k0 = 0; k0 < K; k0 += 4) {
    f4 a[4], bb[4];
#pragma unroll
    for (int i = 0; i < 4; ++i) { int r = 4 * tm + i; a[i] = *(const f4*)(sA + r * 64 + (k0 ^ ((r & 7) << 2))); }
#pragma unroll
    for (int j = 0; j < 4; ++j) bb[j] = *(const f4*)(Bp + (k0 + j) * 64 + 4 * tn);
#pragma unroll
    for (int kk = 0; kk < 4; ++kk)
#pragma unroll
      for (int i = 0; i < 4; ++i)
#pragma unroll
        for (int j = 0; j < 4; ++j)
          acc[i][j] = fmaf(a[i][kk], bb[kk][j], acc[i][j]);
  }
}

// A: LDS swizzled; B: LDS K-major swizzled (sQT)
template <int K>
__device__ __forceinline__ void mm_Aswz_Bswz(const float* __restrict__ sA,
                                             const float* __restrict__ sB,
                                             int tm, int tn, float acc[4][4]) {
  for (int k0 = 0; k0 < K; k0 += 4) {
    f4 a[4], bb[4];
#pragma unroll
    for (int i = 0; i < 4; ++i) { int r = 4 * tm + i; a[i] = *(const f4*)(sA + r * 64 + (k0 ^ ((r & 7) << 2))); }
#pragma unroll
    for (int j = 0; j < 4; ++j) { int kr = k0 + j; bb[j] = *(const f4*)(sB + kr * 64 + ((4 * tn) ^ ((kr & 7) << 2))); }
#pragma unroll
    for (int kk = 0; kk < 4; ++kk)
#pragma unroll
      for (int i = 0; i < 4; ++i)
#pragma unroll
        for (int j = 0; j < 4; ++j)
          acc[i][j] = fmaf(a[i][kk], bb[kk][j], acc[i][j]);
  }
}

__global__ __launch_bounds__(256, 2)
void sdpp_main_kernel(const float* __restrict__ states,
                      const float* __restrict__ b_emb,
                      const float* __restrict__ ws,
                      float* __restrict__ out) {
  // LDS: exactly 81920 B -> 2 blocks/CU
  __shared__ __align__(16) float lds[20480];
  float* sE     = lds;           // swz [64][64] : e   (later reused as node)
  float* sK     = lds + 4096;    // swz [64][64] : k   (later reused as h)
  float* sQT    = lds + 8192;    // swz [64][64] : q^T (k-major)
  float* sV     = lds + 12288;   // plain [64][64]: v  (j-major == K-major for node)
  float* sScr   = lds + 16384;   // swz [64][64] : scores -> weight
  float* sWembT = lds + 4096;    // plain [128][64], phase-2 only (aliases sK+sQT)

  const int t  = threadIdx.x;
  const int tm = t >> 4, tn = t & 15;
  const int b  = blockIdx.x;
  const long sbase = (long)b * (NAGENT * OBSIN);

  // ---- stage WembT (linear copy, conflict-free) ----
  {
    const f4* src = (const f4*)(ws + WS_EMBT);
    f4* dst = (f4*)sWembT;
#pragma unroll
    for (int i = 0; i < 8; ++i) dst[t + 256 * i] = src[t + 256 * i];
  }
  __syncthreads();

  // ---- phase 2: e = relu(S · WembT + b_emb) -> sE ----
  {
    float acc[4][4] = {};
    const float* Ag = states + sbase;
    for (int k0 = 0; k0 < OBSIN; k0 += 4) {
      f4 a[4], bb[4];
#pragma unroll
      for (int i = 0; i < 4; ++i) a[i] = *(const f4*)(Ag + (4 * tm + i) * OBSIN + k0);
#pragma unroll
      for (int j = 0; j < 4; ++j) bb[j] = *(const f4*)(sWembT + (k0 + j) * 64 + 4 * tn);
#pragma unroll
      for (int kk = 0; kk < 4; ++kk)
#pragma unroll
        for (int i = 0; i < 4; ++i)
#pragma unroll
          for (int j = 0; j < 4; ++j)
            acc[i][j] = fmaf(a[i][kk], bb[kk][j], acc[i][j]);
    }
    f4 bias = *(const f4*)(b_emb + 4 * tn);
#pragma unroll
    for (int i = 0; i < 4; ++i) {
      int r = 4 * tm + i;
      f4 v;
#pragma unroll
      for (int j = 0; j < 4; ++j) v[j] = fmaxf(acc[i][j] + bias[j], 0.0f);
      *(f4*)(sE + r * 64 + ((4 * tn) ^ ((r & 7) << 2))) = v;
    }
  }
  __syncthreads();  // sE visible; sWembT reads done before sK/sQT overwritten

  // ---- phase 3: k (x0.125) -> sK ; q -> sQT (transposed) ; v = tanh -> sV ----
  {
    float acc[4][4] = {};
    mm_Aswz_Bplain<64>(sE, ws + WS_KT, tm, tn, acc);
#pragma unroll
    for (int i = 0; i < 4; ++i) {
      int r = 4 * tm + i;
      f4 v;
#pragma unroll
      for (int j = 0; j < 4; ++j) v[j] = acc[i][j] * 0.125f;  // 1/sqrt(D)
      *(f4*)(sK + r * 64 + ((4 * tn) ^ ((r & 7) << 2))) = v;
    }
  }
  {
    float acc[4][4] = {};
    mm_Aswz_Bplain<64>(sE, ws + WS_QT, tm, tn, acc);
#pragma unroll
    for (int i = 0; i < 4; ++i)
#pragma unroll
      for (int j = 0; j < 4; ++j) {
        int d = 4 * tn + j, n = 4 * tm + i;
        sQT[d * 64 + (n ^ ((d & 7) << 2))] = acc[i][j];  // q^T, k-major swizzled
      }
  }
  {
    float acc[4][4] = {};
    mm_Aswz_Bplain<64>(sE, ws + WS_VT, tm, tn, acc);
#pragma unroll
    for (int i = 0; i < 4; ++i) {
      f4 v;
#pragma unroll
      for (int j = 0; j < 4; ++j) v[j] = tanhf(acc[i][j]);
      *(f4*)(sV + (4 * tm + i) * 64 + 4 * tn) = v;  // plain row-major
    }
  }
  __syncthreads();

  // ---- phase 4: scores[i][j] = k_i . q_j -> sScr ----
  {
    float acc[4][4] = {};
    mm_Aswz_Bswz<64>(sK, sQT, tm, tn, acc);
#pragma unroll
    for (int i = 0; i < 4; ++i) {
      int r = 4 * tm + i;
      f4 v;
#pragma unroll
      for (int j = 0; j < 4; ++j) v[j] = acc[i][j];
      *(f4*)(sScr + r * 64 + ((4 * tn) ^ ((r & 7) << 2))) = v;
    }
  }
  __syncthreads();

  // ---- softmax over j per row; write weight to d_out and keep in sScr ----
  {
    const int w = t >> 6, l = t & 63;
    float* wout = out + (long)NBATCH * NAGENT * NACT + (long)b * (NAGENT * NAGENT);
    for (int r = w; r < 64; r += 4) {
      const int wi = r * 64 + (l ^ ((r & 7) << 2));
      float x = sScr[wi];
      float m = x;
#pragma unroll
      for (int mask = 32; mask >= 1; mask >>= 1) m = fmaxf(m, __shfl_xor(m, mask));
      float e = __expf(x - m);
      float s = e;
#pragma unroll
      for (int mask = 32; mask >= 1; mask >>= 1) s += __shfl_xor(s, mask);
      float wv = e / s;
      sScr[wi] = wv;
      wout[r * 64 + l] = wv;
    }
  }
  __syncthreads();

  // ---- phase 5: node = (weight · v) / 64 -> sE region ----
  {
    float acc[4][4] = {};
    mm_Aswz_Bplain<64>(sScr, sV, tm, tn, acc);
#pragma unroll
    for (int i = 0; i < 4; ++i) {
      int r = 4 * tm + i;
      f4 v;
#pragma unroll
      for (int j = 0; j < 4; ++j) v[j] = acc[i][j] * 0.015625f;  // 1/N
      *(f4*)(sE + r * 64 + ((4 * tn) ^ ((r & 7) << 2))) = v;
    }
  }
  __syncthreads();

  // ---- phase 6: h = leaky_relu(node · Wf1T) -> sK region ----
  {
    float acc[4][4] = {};
    mm_Aswz_Bplain<64>(sE, ws + WS_F1T, tm, tn, acc);
#pragma unroll
    for (int i = 0; i < 4; ++i) {
      int r = 4 * tm + i;
      f4 v;
#pragma unroll
      for (int j = 0; j < 4; ++j) { float x = acc[i][j]; v[j] = fmaxf(x, 0.01f * x); }
      *(f4*)(sK + r * 64 + ((4 * tn) ^ ((r & 7) << 2))) = v;
    }
  }
  __syncthreads();

  // ---- phase 7: policy = softmax16(h · Wf2T) ----
  {
    const int r = t >> 2, sub = t & 3;  // 4 lanes per row, 4 actions each
    float acc4[4] = {};
    for (int k0 = 0; k0 < 64; k0 += 4) {
      f4 a = *(const f4*)(sK + r * 64 + (k0 ^ ((r & 7) << 2)));
#pragma unroll
      for (int kk = 0; kk < 4; ++kk) {
        f4 bb = *(const f4*)(ws + WS_F2T + (k0 + kk) * 16 + 4 * sub);
#pragma unroll
        for (int j = 0; j < 4; ++j) acc4[j] = fmaf(a[kk], bb[j], acc4[j]);
      }
    }
    float m = fmaxf(fmaxf(acc4[0], acc4[1]), fmaxf(acc4[2], acc4[3]));
    m = fmaxf(m, __shfl_xor(m, 1));
    m = fmaxf(m, __shfl_xor(m, 2));
    f4 ev;
    float s = 0.0f;
#pragma unroll
    for (int j = 0; j < 4; ++j) { ev[j] = __expf(acc4[j] - m); s += ev[j]; }
    s += __shfl_xor(s, 1);
    s += __shfl_xor(s, 2);
    float inv = 1.0f / s;
    f4 p;
#pragma unroll
    for (int j = 0; j < 4; ++j) p[j] = ev[j] * inv;
    *(f4*)(out + (long)b * (NAGENT * NACT) + r * 16 + 4 * sub) = p;
  }
}

extern "C" void kernel_launch(void* const* d_in, const int* in_sizes, int n_in,
                              void* d_out, int out_size, void* d_ws, size_t ws_size,
                              hipStream_t stream) {
  const float* states = (const float*)d_in[0];
  const float* W_emb  = (const float*)d_in[1];
  const float* b_emb  = (const float*)d_in[2];
  const float* W_k    = (const float*)d_in[3];
  const float* W_q    = (const float*)d_in[4];
  const float* W_v    = (const float*)d_in[5];
  const float* W_f1   = (const float*)d_in[6];
  const float* W_f2   = (const float*)d_in[7];
  float* ws  = (float*)d_ws;
  float* out = (float*)d_out;

  hipLaunchKernelGGL(transpose_weights_kernel, dim3((WS_TOTAL + 255) / 256), dim3(256), 0, stream,
                     W_emb, W_k, W_q, W_v, W_f1, W_f2, ws);
  hipLaunchKernelGGL(sdpp_main_kernel, dim3(NBATCH), dim3(256), 0, stream,
                     states, b_emb, ws, out);
}

// Round 2
// 411.456 us; speedup vs baseline: 4.6567x; 4.6567x over previous
//
#include <hip/hip_runtime.h>
#include <math.h>

typedef float f32x4 __attribute__((ext_vector_type(4)));
typedef short bf8_t __attribute__((ext_vector_type(8)));  // 8 bf16 in 4 VGPRs

#define NBATCH 4096
#define NAGENT 64
#define OBSIN  128
#define DDIM   64
#define NACT   16

// d_ws layout in shorts (bf16), all weights kept in ORIGINAL row-major layout
// (rows = output index, K contiguous) — exactly what the MFMA B-operand wants.
#define EMB_HI 0        // [64][128]
#define EMB_LO 8192
#define WK_HI  16384    // [64][64]
#define WK_LO  20480
#define WQ_HI  24576
#define WQ_LO  28672
#define WV_HI  32768
#define WV_LO  36864
#define WF1_HI 40960
#define WF1_LO 45056
#define WF2_HI 49152    // [16][64]
#define WF2_LO 50176
#define WS_ELEMS 51200  // 102400 B, same footprint as round-1 ws

__device__ __forceinline__ short f2bf(float x) {  // RNE float->bf16 bits
  unsigned u = __float_as_uint(x);
  unsigned r = (u + 0x7fffu + ((u >> 16) & 1u)) >> 16;
  return (short)r;
}
__device__ __forceinline__ float bf2f(short h) {
  return __uint_as_float(((unsigned)(unsigned short)h) << 16);
}

__global__ void prep_weights(const float* __restrict__ W_emb, const float* __restrict__ W_k,
                             const float* __restrict__ W_q,   const float* __restrict__ W_v,
                             const float* __restrict__ W_f1,  const float* __restrict__ W_f2,
                             short* __restrict__ ws) {
  int idx = blockIdx.x * 256 + threadIdx.x;
  float x; int hi_off, lo_off, i;
  if (idx < 8192)       { i = idx;         x = W_emb[i]; hi_off = EMB_HI; lo_off = EMB_LO; }
  else if (idx < 12288) { i = idx - 8192;  x = W_k[i];   hi_off = WK_HI;  lo_off = WK_LO;  }
  else if (idx < 16384) { i = idx - 12288; x = W_q[i];   hi_off = WQ_HI;  lo_off = WQ_LO;  }
  else if (idx < 20480) { i = idx - 16384; x = W_v[i];   hi_off = WV_HI;  lo_off = WV_LO;  }
  else if (idx < 24576) { i = idx - 20480; x = W_f1[i];  hi_off = WF1_HI; lo_off = WF1_LO; }
  else if (idx < 25600) { i = idx - 24576; x = W_f2[i];  hi_off = WF2_HI; lo_off = WF2_LO; }
  else return;
  short h = f2bf(x);
  ws[hi_off + i] = h;
  ws[lo_off + i] = f2bf(x - bf2f(h));
}

__device__ __forceinline__ f32x4 mfma16(bf8_t a, bf8_t b, f32x4 c) {
  return __builtin_amdgcn_mfma_f32_16x16x32_bf16(a, b, c, 0, 0, 0);
}

// split 8 consecutive fp32 into hi/lo bf16 fragments
__device__ __forceinline__ void split8(f32x4 x0, f32x4 x1, bf8_t& hi, bf8_t& lo) {
#pragma unroll
  for (int j = 0; j < 4; ++j) { short h = f2bf(x0[j]); hi[j] = h;     lo[j] = f2bf(x0[j] - bf2f(h)); }
#pragma unroll
  for (int j = 0; j < 4; ++j) { short h = f2bf(x1[j]); hi[4 + j] = h; lo[4 + j] = f2bf(x1[j] - bf2f(h)); }
}

// read 8 consecutive fp32 from a swizzled [64][64] LDS tile row, split to hi/lo
// swizzle: word(r,c) = r*64 + (c ^ ((r&7)<<2)) — 16B-granule XOR, conflict-free
__device__ __forceinline__ void lds_frag(const float* tile, int row, int k0, bf8_t& hi, bf8_t& lo) {
  const int xorv = (row & 7) << 2;
  f32x4 x0 = *(const f32x4*)(tile + row * 64 + ((k0) ^ xorv));
  f32x4 x1 = *(const f32x4*)(tile + row * 64 + ((k0 + 4) ^ xorv));
  split8(x0, x1, hi, lo);
}

// C = A(64xK, LDS tile) x B(Kx64, pre-split global weights); 3-term bf16 split
__device__ __forceinline__ void gemm_ldsA_gB64(const float* At, const short* wsp, int hi_off, int lo_off,
                                               int w, int lr, int lg, f32x4 acc[4]) {
#pragma unroll
  for (int ks = 0; ks < 2; ++ks) {
    const int k0 = ks * 32 + lg * 8;
    bf8_t ahi, alo; lds_frag(At, 16 * w + lr, k0, ahi, alo);
#pragma unroll
    for (int n0 = 0; n0 < 4; ++n0) {
      const int col = n0 * 16 + lr;
      bf8_t bhi = *(const bf8_t*)(wsp + hi_off + col * 64 + k0);
      bf8_t blo = *(const bf8_t*)(wsp + lo_off + col * 64 + k0);
      acc[n0] = mfma16(ahi, bhi, acc[n0]);
      acc[n0] = mfma16(alo, bhi, acc[n0]);
      acc[n0] = mfma16(ahi, blo, acc[n0]);
    }
  }
}

// C = A x B where B^T rows live in a swizzled LDS tile (Bt[col][k])
__device__ __forceinline__ void gemm_ldsA_ldsB(const float* At, const float* Bt,
                                               int w, int lr, int lg, f32x4 acc[4]) {
#pragma unroll
  for (int ks = 0; ks < 2; ++ks) {
    const int k0 = ks * 32 + lg * 8;
    bf8_t ahi, alo; lds_frag(At, 16 * w + lr, k0, ahi, alo);
#pragma unroll
    for (int n0 = 0; n0 < 4; ++n0) {
      bf8_t bhi, blo; lds_frag(Bt, n0 * 16 + lr, k0, bhi, blo);
      acc[n0] = mfma16(ahi, bhi, acc[n0]);
      acc[n0] = mfma16(alo, bhi, acc[n0]);
      acc[n0] = mfma16(ahi, blo, acc[n0]);
    }
  }
}

// D-fragment -> swizzled LDS tile rows (row = M index)
__device__ __forceinline__ void store_tile(float* tile, int w, int lr, int lg, const f32x4 acc[4]) {
#pragma unroll
  for (int n0 = 0; n0 < 4; ++n0) {
    const int col = n0 * 16 + lr;
#pragma unroll
    for (int r = 0; r < 4; ++r) {
      const int row = 16 * w + 4 * lg + r;
      tile[row * 64 + (col ^ ((row & 7) << 2))] = acc[n0][r];
    }
  }
}

__global__ __launch_bounds__(256, 2)
void sdpp_mfma_kernel(const float* __restrict__ states,
                      const float* __restrict__ b_emb,
                      const short* __restrict__ ws,
                      float* __restrict__ out) {
  __shared__ __align__(16) float lds[16384];  // 64 KB -> 2 blocks/CU
  float* sE  = lds;          // E, later reused for W (softmax weights)
  float* sK  = lds + 4096;   // K, later reused for Node
  float* sQ  = lds + 8192;   // Q, later reused for H
  float* sVT = lds + 12288;  // V^T  (rows = d, K-contig = j)

  const int t  = threadIdx.x;
  const int w  = t >> 6;          // wave id: 16-row stripe
  const int l  = t & 63;
  const int lr = l & 15, lg = l >> 4;
  const int b  = blockIdx.x;

  // ---- Phase 1: E = relu(states · W_emb^T + b_emb) -> sE ----
  {
    f32x4 acc[4];
#pragma unroll
    for (int n0 = 0; n0 < 4; ++n0) acc[n0] = f32x4{0.f, 0.f, 0.f, 0.f};
    const float* Sb = states + (long)b * (NAGENT * OBSIN) + (16 * w + lr) * OBSIN;
#pragma unroll
    for (int ks = 0; ks < 4; ++ks) {
      const int k0 = ks * 32 + lg * 8;
      f32x4 x0 = *(const f32x4*)(Sb + k0);
      f32x4 x1 = *(const f32x4*)(Sb + k0 + 4);
      bf8_t ahi, alo; split8(x0, x1, ahi, alo);
#pragma unroll
      for (int n0 = 0; n0 < 4; ++n0) {
        const int col = n0 * 16 + lr;
        bf8_t bhi = *(const bf8_t*)(ws + EMB_HI + col * 128 + k0);
        bf8_t blo = *(const bf8_t*)(ws + EMB_LO + col * 128 + k0);
        acc[n0] = mfma16(ahi, bhi, acc[n0]);
        acc[n0] = mfma16(alo, bhi, acc[n0]);
        acc[n0] = mfma16(ahi, blo, acc[n0]);
      }
    }
#pragma unroll
    for (int n0 = 0; n0 < 4; ++n0) {
      const int col  = n0 * 16 + lr;
      const float bias = b_emb[col];
#pragma unroll
      for (int r = 0; r < 4; ++r) {
        const int row = 16 * w + 4 * lg + r;
        sE[row * 64 + (col ^ ((row & 7) << 2))] = fmaxf(acc[n0][r] + bias, 0.f);
      }
    }
  }
  __syncthreads();

  // ---- Phase 2: K = 0.125·E·Wk^T -> sK ; Q = E·Wq^T -> sQ ; V = tanh(E·Wv^T) -> sVT ----
  {
    bf8_t a0h, a0l, a1h, a1l;  // E A-frags shared by the three GEMMs
    lds_frag(sE, 16 * w + lr, lg * 8, a0h, a0l);
    lds_frag(sE, 16 * w + lr, 32 + lg * 8, a1h, a1l);

#pragma unroll
    for (int which = 0; which < 3; ++which) {
      const int hi_off = (which == 0) ? WK_HI : (which == 1) ? WQ_HI : WV_HI;
      const int lo_off = (which == 0) ? WK_LO : (which == 1) ? WQ_LO : WV_LO;
      f32x4 acc[4];
#pragma unroll
      for (int n0 = 0; n0 < 4; ++n0) acc[n0] = f32x4{0.f, 0.f, 0.f, 0.f};
#pragma unroll
      for (int n0 = 0; n0 < 4; ++n0) {
        const int col = n0 * 16 + lr;
        {
          const int k0 = lg * 8;
          bf8_t bhi = *(const bf8_t*)(ws + hi_off + col * 64 + k0);
          bf8_t blo = *(const bf8_t*)(ws + lo_off + col * 64 + k0);
          acc[n0] = mfma16(a0h, bhi, acc[n0]);
          acc[n0] = mfma16(a0l, bhi, acc[n0]);
          acc[n0] = mfma16(a0h, blo, acc[n0]);
        }
        {
          const int k0 = 32 + lg * 8;
          bf8_t bhi = *(const bf8_t*)(ws + hi_off + col * 64 + k0);
          bf8_t blo = *(const bf8_t*)(ws + lo_off + col * 64 + k0);
          acc[n0] = mfma16(a1h, bhi, acc[n0]);
          acc[n0] = mfma16(a1l, bhi, acc[n0]);
          acc[n0] = mfma16(a1h, blo, acc[n0]);
        }
      }
      if (which == 0) {        // K, scaled by 1/sqrt(D)
#pragma unroll
        for (int n0 = 0; n0 < 4; ++n0) {
          const int col = n0 * 16 + lr;
#pragma unroll
          for (int r = 0; r < 4; ++r) {
            const int row = 16 * w + 4 * lg + r;
            sK[row * 64 + (col ^ ((row & 7) << 2))] = acc[n0][r] * 0.125f;
          }
        }
      } else if (which == 1) { // Q
        store_tile(sQ, w, lr, lg, acc);
      } else {                 // V -> transposed store: sVT[d][j]
#pragma unroll
        for (int n0 = 0; n0 < 4; ++n0) {
          const int c = n0 * 16 + lr;       // d
#pragma unroll
          for (int r = 0; r < 4; ++r) {
            const int row = 16 * w + 4 * lg + r;  // j
            sVT[c * 64 + (row ^ ((c & 7) << 2))] = tanhf(acc[n0][r]);
          }
        }
      }
    }
  }
  __syncthreads();

  // ---- Phase 3+4: scores = K·Q^T ; row-softmax fully in-register; W -> out + sE ----
  {
    f32x4 acc[4];
#pragma unroll
    for (int n0 = 0; n0 < 4; ++n0) acc[n0] = f32x4{0.f, 0.f, 0.f, 0.f};
    gemm_ldsA_ldsB(sK, sQ, w, lr, lg, acc);

    float* wout = out + (long)NBATCH * NAGENT * NACT + (long)b * (NAGENT * NAGENT);
#pragma unroll
    for (int r = 0; r < 4; ++r) {
      // this lane holds row = 16w+4lg+r at cols {n0*16+lr}; full row lives in the 16-lane lr-group
      float m = fmaxf(fmaxf(acc[0][r], acc[1][r]), fmaxf(acc[2][r], acc[3][r]));
#pragma unroll
      for (int msk = 1; msk < 16; msk <<= 1) m = fmaxf(m, __shfl_xor(m, msk));
      float e[4];
      float s = 0.f;
#pragma unroll
      for (int n0 = 0; n0 < 4; ++n0) { e[n0] = __expf(acc[n0][r] - m); s += e[n0]; }
#pragma unroll
      for (int msk = 1; msk < 16; msk <<= 1) s += __shfl_xor(s, msk);
      const float inv = 1.f / s;
      const int row = 16 * w + 4 * lg + r;
#pragma unroll
      for (int n0 = 0; n0 < 4; ++n0) {
        const int col = n0 * 16 + lr;
        const float wv = e[n0] * inv;
        wout[row * 64 + col] = wv;
        sE[row * 64 + (col ^ ((row & 7) << 2))] = wv;
      }
    }
  }
  __syncthreads();

  // ---- Phase 5: Node = (W · V)/64 -> sK ----
  {
    f32x4 acc[4];
#pragma unroll
    for (int n0 = 0; n0 < 4; ++n0) acc[n0] = f32x4{0.f, 0.f, 0.f, 0.f};
    gemm_ldsA_ldsB(sE, sVT, w, lr, lg, acc);
#pragma unroll
    for (int n0 = 0; n0 < 4; ++n0) {
      const int col = n0 * 16 + lr;
#pragma unroll
      for (int r = 0; r < 4; ++r) {
        const int row = 16 * w + 4 * lg + r;
        sK[row * 64 + (col ^ ((row & 7) << 2))] = acc[n0][r] * 0.015625f;
      }
    }
  }
  __syncthreads();

  // ---- Phase 6: H = leaky_relu(Node · Wf1^T) -> sQ ----
  {
    f32x4 acc[4];
#pragma unroll
    for (int n0 = 0; n0 < 4; ++n0) acc[n0] = f32x4{0.f, 0.f, 0.f, 0.f};
    gemm_ldsA_gB64(sK, ws, WF1_HI, WF1_LO, w, lr, lg, acc);
#pragma unroll
    for (int n0 = 0; n0 < 4; ++n0) {
      const int col = n0 * 16 + lr;
#pragma unroll
      for (int r = 0; r < 4; ++r) {
        const int row = 16 * w + 4 * lg + r;
        const float x = acc[n0][r];
        sQ[row * 64 + (col ^ ((row & 7) << 2))] = fmaxf(x, 0.01f * x);
      }
    }
  }
  __syncthreads();

  // ---- Phase 7: policy = softmax16(H · Wf2^T) -> out ----
  {
    f32x4 acc = f32x4{0.f, 0.f, 0.f, 0.f};
#pragma unroll
    for (int ks = 0; ks < 2; ++ks) {
      const int k0 = ks * 32 + lg * 8;
      bf8_t ahi, alo; lds_frag(sQ, 16 * w + lr, k0, ahi, alo);
      bf8_t bhi = *(const bf8_t*)(ws + WF2_HI + lr * 64 + k0);  // col = lr (16 actions)
      bf8_t blo = *(const bf8_t*)(ws + WF2_LO + lr * 64 + k0);
      acc = mfma16(ahi, bhi, acc);
      acc = mfma16(alo, bhi, acc);
      acc = mfma16(ahi, blo, acc);
    }
    float* pout = out + (long)b * (NAGENT * NACT);
#pragma unroll
    for (int r = 0; r < 4; ++r) {
      float m = acc[r];
#pragma unroll
      for (int msk = 1; msk < 16; msk <<= 1) m = fmaxf(m, __shfl_xor(m, msk));
      float e = __expf(acc[r] - m);
      float s = e;
#pragma unroll
      for (int msk = 1; msk < 16; msk <<= 1) s += __shfl_xor(s, msk);
      const int row = 16 * w + 4 * lg + r;
      pout[row * 16 + lr] = e / s;
    }
  }
}

extern "C" void kernel_launch(void* const* d_in, const int* in_sizes, int n_in,
                              void* d_out, int out_size, void* d_ws, size_t ws_size,
                              hipStream_t stream) {
  const float* states = (const float*)d_in[0];
  const float* W_emb  = (const float*)d_in[1];
  const float* b_emb  = (const float*)d_in[2];
  const float* W_k    = (const float*)d_in[3];
  const float* W_q    = (const float*)d_in[4];
  const float* W_v    = (const float*)d_in[5];
  const float* W_f1   = (const float*)d_in[6];
  const float* W_f2   = (const float*)d_in[7];
  short* ws  = (short*)d_ws;
  float* out = (float*)d_out;

  hipLaunchKernelGGL(prep_weights, dim3(100), dim3(256), 0, stream,
                     W_emb, W_k, W_q, W_v, W_f1, W_f2, ws);
  hipLaunchKernelGGL(sdpp_mfma_kernel, dim3(NBATCH), dim3(256), 0, stream,
                     states, b_emb, ws, out);
}

// Round 3
// 382.069 us; speedup vs baseline: 5.0148x; 1.0769x over previous
//
#include <hip/hip_runtime.h>
#include <math.h>

typedef float f32x4 __attribute__((ext_vector_type(4)));
typedef short bf8_t __attribute__((ext_vector_type(8)));  // 8 bf16 (4 VGPRs)

#define NBATCH 4096
#define NAGENT 64
#define OBSIN  128
#define NACT   16

// ws layout (shorts). Weights row-major [out][k], pre-split bf16 hi/lo.
#define EMB_HI 0        // [64][128]
#define EMB_LO 8192
#define WV_HI  16384    // [64][64]
#define WV_LO  20480
#define WF1_HI 24576    // [64][64]
#define WF1_LO 28672
#define WF2_HI 32768    // [16][64]
#define WF2_LO 33792
#define MT_HI  34816    // [64][64]  MT[a][b] = 0.125 * sum_d Wk[d][b]*Wq[d][a]
#define MT_LO  38912
#define SPLIT_ELEMS 17408

__device__ __forceinline__ short f2bf(float x) {  // RNE fp32 -> bf16 bits
  unsigned u = __float_as_uint(x);
  return (short)((u + 0x7fffu + ((u >> 16) & 1u)) >> 16);
}
__device__ __forceinline__ float bf2f(short h) {
  return __uint_as_float(((unsigned)(unsigned short)h) << 16);
}
__device__ __forceinline__ float tanh_fast(float x) {
  x = fminf(fmaxf(x, -15.f), 15.f);
  float e = __expf(2.f * x);
  return (e - 1.f) / (e + 1.f);
}

__global__ void prep_weights(const float* __restrict__ W_emb, const float* __restrict__ W_k,
                             const float* __restrict__ W_q,   const float* __restrict__ W_v,
                             const float* __restrict__ W_f1,  const float* __restrict__ W_f2,
                             short* __restrict__ ws) {
  __shared__ float sk[4096], sq[4096];
  const int blk = blockIdx.x, t = threadIdx.x;
  if (blk < 68) {
    const int idx = blk * 256 + t;
    if (idx >= SPLIT_ELEMS) return;
    float x; int hi, lo, i;
    if (idx < 8192)       { i = idx;         x = W_emb[i]; hi = EMB_HI; lo = EMB_LO; }
    else if (idx < 12288) { i = idx - 8192;  x = W_v[i];   hi = WV_HI;  lo = WV_LO;  }
    else if (idx < 16384) { i = idx - 12288; x = W_f1[i];  hi = WF1_HI; lo = WF1_LO; }
    else                  { i = idx - 16384; x = W_f2[i];  hi = WF2_HI; lo = WF2_LO; }
    short h = f2bf(x);
    ws[hi + i] = h;
    ws[lo + i] = f2bf(x - bf2f(h));
  } else {
    // MT[a][b] = 0.125 * sum_d Wk[d][b] * Wq[d][a]
    for (int i = t; i < 4096; i += 256) { sk[i] = W_k[i]; sq[i] = W_q[i]; }
    __syncthreads();
    for (int e = t; e < 4096; e += 256) {
      const int a = e >> 6, bcol = e & 63;
      float s = 0.f;
      for (int d = 0; d < 64; ++d) s = fmaf(sk[d * 64 + bcol], sq[d * 64 + a], s);
      s *= 0.125f;
      short h = f2bf(s);
      ws[MT_HI + e] = h;
      ws[MT_LO + e] = f2bf(s - bf2f(h));
    }
  }
}

__device__ __forceinline__ f32x4 mfma16(bf8_t a, bf8_t b, f32x4 c) {
  return __builtin_amdgcn_mfma_f32_16x16x32_bf16(a, b, c, 0, 0, 0);
}
__device__ __forceinline__ void mfma3(f32x4& acc, bf8_t ah, bf8_t al, bf8_t bh, bf8_t bl) {
  acc = mfma16(ah, bh, acc);
  acc = mfma16(al, bh, acc);
  acc = mfma16(ah, bl, acc);
}

// bf16 tile [64][64] shorts, XOR-swizzled in 8-short (16B) granules:
// idx(row,k) = row*64 + (k ^ ((row&7)<<3)) — conflict-free b128 column reads.
__device__ __forceinline__ void ldA(const short* th, const short* tl, int row, int k0,
                                    bf8_t& h, bf8_t& l) {
  const int idx = row * 64 + (k0 ^ ((row & 7) << 3));
  h = *(const bf8_t*)(th + idx);
  l = *(const bf8_t*)(tl + idx);
}
__device__ __forceinline__ void stElem(short* th, short* tl, int row, int col, float x) {
  const int idx = row * 64 + (col ^ ((row & 7) << 3));
  short h = f2bf(x);
  th[idx] = h;
  tl[idx] = f2bf(x - bf2f(h));
}

__global__ __launch_bounds__(256, 5)
void sdpp_kernel(const float* __restrict__ states, const float* __restrict__ b_emb,
                 const short* __restrict__ ws, float* __restrict__ out) {
  // 32 KB LDS total -> 5 blocks/CU.
  __shared__ __align__(16) short lds[16384];
  short* t1h = lds;          // tile1 hi: E, then V^T
  short* t1l = lds + 4096;   // tile1 lo
  short* t2h = lds + 8192;   // tile2 hi: T, then W, Node, H
  short* t2l = lds + 12288;  // tile2 lo

  const int t = threadIdx.x, w = t >> 6, l = t & 63;
  const int lr = l & 15, lg = l >> 4;
  const int b = blockIdx.x;
  const int arow = 16 * w + lr;      // this lane's A-operand row
  const int k0a = lg * 8, k0b = 32 + lg * 8;

  // ---- Phase 1: E = relu(states · Wemb^T + b) -> tile1 ----
  {
    f32x4 eacc[4];
#pragma unroll
    for (int i = 0; i < 4; ++i) eacc[i] = f32x4{0.f, 0.f, 0.f, 0.f};
    const float* Sb = states + (long)b * (NAGENT * OBSIN) + arow * OBSIN;
#pragma unroll
    for (int ks = 0; ks < 4; ++ks) {
      const int k0 = ks * 32 + lg * 8;
      f32x4 x0 = *(const f32x4*)(Sb + k0);
      f32x4 x1 = *(const f32x4*)(Sb + k0 + 4);
      bf8_t ah, al;
#pragma unroll
      for (int j = 0; j < 4; ++j) { short h = f2bf(x0[j]); ah[j] = h;     al[j] = f2bf(x0[j] - bf2f(h)); }
#pragma unroll
      for (int j = 0; j < 4; ++j) { short h = f2bf(x1[j]); ah[4 + j] = h; al[4 + j] = f2bf(x1[j] - bf2f(h)); }
#pragma unroll
      for (int n0 = 0; n0 < 4; ++n0) {
        const int col = n0 * 16 + lr;
        bf8_t bh = *(const bf8_t*)(ws + EMB_HI + col * 128 + k0);
        bf8_t bl = *(const bf8_t*)(ws + EMB_LO + col * 128 + k0);
        mfma3(eacc[n0], ah, al, bh, bl);
      }
    }
#pragma unroll
    for (int n0 = 0; n0 < 4; ++n0) {
      const int col = n0 * 16 + lr;
      const float bias = b_emb[col];
#pragma unroll
      for (int r = 0; r < 4; ++r)
        stElem(t1h, t1l, 16 * w + 4 * lg + r, col, fmaxf(eacc[n0][r] + bias, 0.f));
    }
  }
  // No barrier: T and V read only this wave's own E stripe (intra-wave LDS order).

  bf8_t eh0, el0, eh1, el1;  // E A-fragments, reused by T and V GEMMs
  ldA(t1h, t1l, arow, k0a, eh0, el0);
  ldA(t1h, t1l, arow, k0b, eh1, el1);

  // ---- T = E · MT -> tile2 (own stripe) ----
  {
    f32x4 tacc[4];
#pragma unroll
    for (int i = 0; i < 4; ++i) tacc[i] = f32x4{0.f, 0.f, 0.f, 0.f};
#pragma unroll
    for (int n0 = 0; n0 < 4; ++n0) {
      const int col = n0 * 16 + lr;
      bf8_t bh, bl;
      bh = *(const bf8_t*)(ws + MT_HI + col * 64 + k0a);
      bl = *(const bf8_t*)(ws + MT_LO + col * 64 + k0a);
      mfma3(tacc[n0], eh0, el0, bh, bl);
      bh = *(const bf8_t*)(ws + MT_HI + col * 64 + k0b);
      bl = *(const bf8_t*)(ws + MT_LO + col * 64 + k0b);
      mfma3(tacc[n0], eh1, el1, bh, bl);
    }
#pragma unroll
    for (int n0 = 0; n0 < 4; ++n0)
#pragma unroll
      for (int r = 0; r < 4; ++r)
        stElem(t2h, t2l, 16 * w + 4 * lg + r, n0 * 16 + lr, tacc[n0][r]);
  }

  // ---- V = E · Wv^T -> registers (stored as V^T after barrier) ----
  f32x4 vacc[4];
#pragma unroll
  for (int i = 0; i < 4; ++i) vacc[i] = f32x4{0.f, 0.f, 0.f, 0.f};
  {
#pragma unroll
    for (int n0 = 0; n0 < 4; ++n0) {
      const int col = n0 * 16 + lr;
      bf8_t bh, bl;
      bh = *(const bf8_t*)(ws + WV_HI + col * 64 + k0a);
      bl = *(const bf8_t*)(ws + WV_LO + col * 64 + k0a);
      mfma3(vacc[n0], eh0, el0, bh, bl);
      bh = *(const bf8_t*)(ws + WV_HI + col * 64 + k0b);
      bl = *(const bf8_t*)(ws + WV_LO + col * 64 + k0b);
      mfma3(vacc[n0], eh1, el1, bh, bl);
    }
  }

  __syncthreads();  // B1: all E stores visible for cross-wave reads

  // ---- scores = T · E^T (A = own T stripe, B = E all rows) ----
  f32x4 sacc[4];
#pragma unroll
  for (int i = 0; i < 4; ++i) sacc[i] = f32x4{0.f, 0.f, 0.f, 0.f};
  {
    bf8_t th0, tl0, th1, tl1;
    ldA(t2h, t2l, arow, k0a, th0, tl0);
    ldA(t2h, t2l, arow, k0b, th1, tl1);
#pragma unroll
    for (int n0 = 0; n0 < 4; ++n0) {
      const int brow = n0 * 16 + lr;
      bf8_t bh, bl;
      ldA(t1h, t1l, brow, k0a, bh, bl);
      mfma3(sacc[n0], th0, tl0, bh, bl);
      ldA(t1h, t1l, brow, k0b, bh, bl);
      mfma3(sacc[n0], th1, tl1, bh, bl);
    }
  }

  __syncthreads();  // B2: all cross-wave E reads done; tile1 free for V^T

  // ---- V^T -> tile1 (VT[d][j] = tanh(v[j][d])) ----
#pragma unroll
  for (int n0 = 0; n0 < 4; ++n0) {
    const int d = n0 * 16 + lr;
#pragma unroll
    for (int r = 0; r < 4; ++r)
      stElem(t1h, t1l, d, 16 * w + 4 * lg + r, tanh_fast(vacc[n0][r]));
  }

  // ---- softmax over cols -> W: global out + tile2 (own stripe, overwrites T) ----
  {
    float* wout = out + (long)NBATCH * NAGENT * NACT + (long)b * (NAGENT * NAGENT);
#pragma unroll
    for (int r = 0; r < 4; ++r) {
      float m = fmaxf(fmaxf(sacc[0][r], sacc[1][r]), fmaxf(sacc[2][r], sacc[3][r]));
#pragma unroll
      for (int msk = 1; msk < 16; msk <<= 1) m = fmaxf(m, __shfl_xor(m, msk));
      float ev[4];
      float s = 0.f;
#pragma unroll
      for (int n0 = 0; n0 < 4; ++n0) { ev[n0] = __expf(sacc[n0][r] - m); s += ev[n0]; }
#pragma unroll
      for (int msk = 1; msk < 16; msk <<= 1) s += __shfl_xor(s, msk);
      const float inv = 1.f / s;
      const int row = 16 * w + 4 * lg + r;
#pragma unroll
      for (int n0 = 0; n0 < 4; ++n0) {
        const int col = n0 * 16 + lr;
        const float wv = ev[n0] * inv;
        wout[row * 64 + col] = wv;
        stElem(t2h, t2l, row, col, wv);
      }
    }
  }

  __syncthreads();  // B3: V^T visible for cross-wave reads

  // ---- Node = (W · V)/64 -> tile2 own stripe (A = own W stripe, B = VT) ----
  {
    bf8_t wh0, wl0, wh1, wl1;
    ldA(t2h, t2l, arow, k0a, wh0, wl0);
    ldA(t2h, t2l, arow, k0b, wh1, wl1);
    f32x4 nacc[4];
#pragma unroll
    for (int i = 0; i < 4; ++i) nacc[i] = f32x4{0.f, 0.f, 0.f, 0.f};
#pragma unroll
    for (int n0 = 0; n0 < 4; ++n0) {
      const int brow = n0 * 16 + lr;
      bf8_t bh, bl;
      ldA(t1h, t1l, brow, k0a, bh, bl);
      mfma3(nacc[n0], wh0, wl0, bh, bl);
      ldA(t1h, t1l, brow, k0b, bh, bl);
      mfma3(nacc[n0], wh1, wl1, bh, bl);
    }
#pragma unroll
    for (int n0 = 0; n0 < 4; ++n0)
#pragma unroll
      for (int r = 0; r < 4; ++r)
        stElem(t2h, t2l, 16 * w + 4 * lg + r, n0 * 16 + lr, nacc[n0][r] * 0.015625f);
  }

  // ---- H = leaky_relu(Node · Wf1^T) -> tile2 own stripe ----
  {
    bf8_t nh0, nl0, nh1, nl1;
    ldA(t2h, t2l, arow, k0a, nh0, nl0);
    ldA(t2h, t2l, arow, k0b, nh1, nl1);
    f32x4 hacc[4];
#pragma unroll
    for (int i = 0; i < 4; ++i) hacc[i] = f32x4{0.f, 0.f, 0.f, 0.f};
#pragma unroll
    for (int n0 = 0; n0 < 4; ++n0) {
      const int col = n0 * 16 + lr;
      bf8_t bh, bl;
      bh = *(const bf8_t*)(ws + WF1_HI + col * 64 + k0a);
      bl = *(const bf8_t*)(ws + WF1_LO + col * 64 + k0a);
      mfma3(hacc[n0], nh0, nl0, bh, bl);
      bh = *(const bf8_t*)(ws + WF1_HI + col * 64 + k0b);
      bl = *(const bf8_t*)(ws + WF1_LO + col * 64 + k0b);
      mfma3(hacc[n0], nh1, nl1, bh, bl);
    }
#pragma unroll
    for (int n0 = 0; n0 < 4; ++n0)
#pragma unroll
      for (int r = 0; r < 4; ++r) {
        const float x = hacc[n0][r];
        stElem(t2h, t2l, 16 * w + 4 * lg + r, n0 * 16 + lr, fmaxf(x, 0.01f * x));
      }
  }

  // ---- policy = softmax16(H · Wf2^T) -> out ----
  {
    bf8_t hh0, hl0, hh1, hl1;
    ldA(t2h, t2l, arow, k0a, hh0, hl0);
    ldA(t2h, t2l, arow, k0b, hh1, hl1);
    f32x4 p = f32x4{0.f, 0.f, 0.f, 0.f};
    bf8_t bh, bl;
    bh = *(const bf8_t*)(ws + WF2_HI + lr * 64 + k0a);
    bl = *(const bf8_t*)(ws + WF2_LO + lr * 64 + k0a);
    mfma3(p, hh0, hl0, bh, bl);
    bh = *(const bf8_t*)(ws + WF2_HI + lr * 64 + k0b);
    bl = *(const bf8_t*)(ws + WF2_LO + lr * 64 + k0b);
    mfma3(p, hh1, hl1, bh, bl);

    float* pout = out + (long)b * (NAGENT * NACT);
#pragma unroll
    for (int r = 0; r < 4; ++r) {
      float m = p[r];
#pragma unroll
      for (int msk = 1; msk < 16; msk <<= 1) m = fmaxf(m, __shfl_xor(m, msk));
      float e = __expf(p[r] - m);
      float s = e;
#pragma unroll
      for (int msk = 1; msk < 16; msk <<= 1) s += __shfl_xor(s, msk);
      pout[(16 * w + 4 * lg + r) * 16 + lr] = e / s;
    }
  }
}

extern "C" void kernel_launch(void* const* d_in, const int* in_sizes, int n_in,
                              void* d_out, int out_size, void* d_ws, size_t ws_size,
                              hipStream_t stream) {
  const float* states = (const float*)d_in[0];
  const float* W_emb  = (const float*)d_in[1];
  const float* b_emb  = (const float*)d_in[2];
  const float* W_k    = (const float*)d_in[3];
  const float* W_q    = (const float*)d_in[4];
  const float* W_v    = (const float*)d_in[5];
  const float* W_f1   = (const float*)d_in[6];
  const float* W_f2   = (const float*)d_in[7];
  short* ws  = (short*)d_ws;
  float* out = (float*)d_out;

  hipLaunchKernelGGL(prep_weights, dim3(69), dim3(256), 0, stream,
                     W_emb, W_k, W_q, W_v, W_f1, W_f2, ws);
  hipLaunchKernelGGL(sdpp_kernel, dim3(NBATCH), dim3(256), 0, stream,
                     states, b_emb, ws, out);
}

// Round 4
// 300.857 us; speedup vs baseline: 6.3685x; 1.2699x over previous
//
#include <hip/hip_runtime.h>
#include <math.h>

typedef float f32x4 __attribute__((ext_vector_type(4)));
typedef short bf8_t __attribute__((ext_vector_type(8)));  // 8 bf16 (4 VGPRs)

#define NBATCH 4096
#define NAGENT 64
#define OBSIN  128
#define NACT   16

// ws layout (shorts): plain bf16 weights, row-major [out][k]
#define W_EMB 0      // [64][128]
#define W_V   8192   // [64][64]
#define W_F1  12288  // [64][64]
#define W_F2  16384  // [16][64]
#define W_MT  17408  // [64][64]  MT[a][b] = 0.125 * sum_d Wk[d][b]*Wq[d][a]
#define SPLIT_ELEMS 17408

__device__ __forceinline__ short f2bf(float x) {  // RNE fp32 -> bf16 bits
  unsigned u = __float_as_uint(x);
  return (short)((u + 0x7fffu + ((u >> 16) & 1u)) >> 16);
}
__device__ __forceinline__ float tanh_fast(float x) {
  x = fminf(fmaxf(x, -15.f), 15.f);
  float e = __expf(2.f * x);
  return (e - 1.f) / (e + 1.f);
}

__global__ void prep_weights(const float* __restrict__ W_emb, const float* __restrict__ W_k,
                             const float* __restrict__ W_q,   const float* __restrict__ W_v,
                             const float* __restrict__ W_f1,  const float* __restrict__ W_f2,
                             short* __restrict__ ws) {
  __shared__ float sk[4096], sq[4096];
  const int blk = blockIdx.x, t = threadIdx.x;
  if (blk < 68) {
    const int idx = blk * 256 + t;
    if (idx >= SPLIT_ELEMS) return;
    float x; int off, i;
    if (idx < 8192)       { i = idx;         x = W_emb[i]; off = W_EMB; }
    else if (idx < 12288) { i = idx - 8192;  x = W_v[i];   off = W_V;   }
    else if (idx < 16384) { i = idx - 12288; x = W_f1[i];  off = W_F1;  }
    else                  { i = idx - 16384; x = W_f2[i];  off = W_F2;  }
    ws[off + i] = f2bf(x);
  } else {
    // MT stored row-major [a][b]: ws[W_MT + a*64 + b] = 0.125 * sum_d Wk[d][b]*Wq[d][a]
    for (int i = t; i < 4096; i += 256) { sk[i] = W_k[i]; sq[i] = W_q[i]; }
    __syncthreads();
    for (int e = t; e < 4096; e += 256) {
      const int a = e >> 6, bcol = e & 63;
      float s = 0.f;
      for (int d = 0; d < 64; ++d) s = fmaf(sk[d * 64 + bcol], sq[d * 64 + a], s);
      ws[W_MT + e] = f2bf(s * 0.125f);
    }
  }
}

__device__ __forceinline__ f32x4 mfma16(bf8_t a, bf8_t b, f32x4 c) {
  return __builtin_amdgcn_mfma_f32_16x16x32_bf16(a, b, c, 0, 0, 0);
}

// bf16 tile [64][64] shorts, XOR-swizzled in 8-short (16B) granules.
__device__ __forceinline__ bf8_t ld8(const short* tile, int row, int k0) {
  return *(const bf8_t*)(tile + row * 64 + (k0 ^ ((row & 7) << 3)));
}
__device__ __forceinline__ void stE(short* tile, int row, int col, float x) {
  tile[row * 64 + (col ^ ((row & 7) << 3))] = f2bf(x);
}

__global__ __launch_bounds__(256, 8)
void sdpp_kernel(const float* __restrict__ states, const float* __restrict__ b_emb,
                 const short* __restrict__ ws, float* __restrict__ out) {
  // 16 KB LDS -> 8 blocks/CU (32 waves = 100% occupancy)
  __shared__ __align__(16) short lds[8192];
  short* t1 = lds;         // E, then V^T
  short* t2 = lds + 4096;  // T, then W, Node, H

  const int t = threadIdx.x, w = t >> 6, l = t & 63;
  const int lr = l & 15, lg = l >> 4;
  const int b = blockIdx.x;
  const int arow = 16 * w + lr;       // this lane's A-operand row
  const int k0a = lg * 8, k0b = 32 + lg * 8;

  // ---- Phase 1: E = relu(states · Wemb^T + b) -> t1 ----
  {
    f32x4 eacc[4];
#pragma unroll
    for (int i = 0; i < 4; ++i) eacc[i] = f32x4{0.f, 0.f, 0.f, 0.f};
    const float* Sb = states + (long)b * (NAGENT * OBSIN) + arow * OBSIN;
#pragma unroll
    for (int ks = 0; ks < 4; ++ks) {
      const int k0 = ks * 32 + lg * 8;
      f32x4 x0 = *(const f32x4*)(Sb + k0);
      f32x4 x1 = *(const f32x4*)(Sb + k0 + 4);
      bf8_t ah;
#pragma unroll
      for (int j = 0; j < 4; ++j) { ah[j] = f2bf(x0[j]); ah[4 + j] = f2bf(x1[j]); }
#pragma unroll
      for (int n0 = 0; n0 < 4; ++n0) {
        const int col = n0 * 16 + lr;
        bf8_t bh = *(const bf8_t*)(ws + W_EMB + col * 128 + k0);
        eacc[n0] = mfma16(ah, bh, eacc[n0]);
      }
    }
#pragma unroll
    for (int n0 = 0; n0 < 4; ++n0) {
      const int col = n0 * 16 + lr;
      const float bias = b_emb[col];
#pragma unroll
      for (int r = 0; r < 4; ++r)
        stE(t1, 16 * w + 4 * lg + r, col, fmaxf(eacc[n0][r] + bias, 0.f));
    }
  }
  // No barrier: T reads only this wave's own E stripe (intra-wave LDS ordering).

  // ---- T = E · MT -> t2 (own stripe) ----
  {
    bf8_t e0 = ld8(t1, arow, k0a), e1 = ld8(t1, arow, k0b);
    f32x4 tacc[4];
#pragma unroll
    for (int i = 0; i < 4; ++i) tacc[i] = f32x4{0.f, 0.f, 0.f, 0.f};
#pragma unroll
    for (int n0 = 0; n0 < 4; ++n0) {
      const int col = n0 * 16 + lr;
      tacc[n0] = mfma16(e0, *(const bf8_t*)(ws + W_MT + col * 64 + k0a), tacc[n0]);
      tacc[n0] = mfma16(e1, *(const bf8_t*)(ws + W_MT + col * 64 + k0b), tacc[n0]);
    }
#pragma unroll
    for (int n0 = 0; n0 < 4; ++n0)
#pragma unroll
      for (int r = 0; r < 4; ++r)
        stE(t2, 16 * w + 4 * lg + r, n0 * 16 + lr, tacc[n0][r]);
  }

  __syncthreads();  // B1: all E (t1) and own T (t2) stores visible

  // ---- scores = T · E^T (A = own T stripe, B = E all rows, cross-wave) ----
  f32x4 sacc[4];
#pragma unroll
  for (int i = 0; i < 4; ++i) sacc[i] = f32x4{0.f, 0.f, 0.f, 0.f};
  {
    bf8_t th0 = ld8(t2, arow, k0a), th1 = ld8(t2, arow, k0b);
#pragma unroll
    for (int n0 = 0; n0 < 4; ++n0) {
      const int brow = n0 * 16 + lr;
      sacc[n0] = mfma16(th0, ld8(t1, brow, k0a), sacc[n0]);
      sacc[n0] = mfma16(th1, ld8(t1, brow, k0b), sacc[n0]);
    }
  }

  // ---- softmax over cols -> W: global out + t2 own stripe (overwrites T) ----
  {
    float* wout = out + (long)NBATCH * NAGENT * NACT + (long)b * (NAGENT * NAGENT);
#pragma unroll
    for (int r = 0; r < 4; ++r) {
      float m = fmaxf(fmaxf(sacc[0][r], sacc[1][r]), fmaxf(sacc[2][r], sacc[3][r]));
#pragma unroll
      for (int msk = 1; msk < 16; msk <<= 1) m = fmaxf(m, __shfl_xor(m, msk));
      float ev[4];
      float s = 0.f;
#pragma unroll
      for (int n0 = 0; n0 < 4; ++n0) { ev[n0] = __expf(sacc[n0][r] - m); s += ev[n0]; }
#pragma unroll
      for (int msk = 1; msk < 16; msk <<= 1) s += __shfl_xor(s, msk);
      const float inv = 1.f / s;
      const int row = 16 * w + 4 * lg + r;
#pragma unroll
      for (int n0 = 0; n0 < 4; ++n0) {
        const int col = n0 * 16 + lr;
        const float wv = ev[n0] * inv;
        wout[row * 64 + col] = wv;
        stE(t2, row, col, wv);
      }
    }
  }

  // ---- V = E · Wv^T -> registers (E own stripe, pre-B2) ----
  f32x4 vacc[4];
#pragma unroll
  for (int i = 0; i < 4; ++i) vacc[i] = f32x4{0.f, 0.f, 0.f, 0.f};
  {
    bf8_t e0 = ld8(t1, arow, k0a), e1 = ld8(t1, arow, k0b);
#pragma unroll
    for (int n0 = 0; n0 < 4; ++n0) {
      const int col = n0 * 16 + lr;
      vacc[n0] = mfma16(e0, *(const bf8_t*)(ws + W_V + col * 64 + k0a), vacc[n0]);
      vacc[n0] = mfma16(e1, *(const bf8_t*)(ws + W_V + col * 64 + k0b), vacc[n0]);
    }
  }

  __syncthreads();  // B2: all cross-wave E reads done; t1 free for V^T

  // ---- V^T -> t1 (VT[d][j] = tanh(v[j][d])) ----
#pragma unroll
  for (int n0 = 0; n0 < 4; ++n0) {
    const int d = n0 * 16 + lr;
#pragma unroll
    for (int r = 0; r < 4; ++r)
      stE(t1, d, 16 * w + 4 * lg + r, tanh_fast(vacc[n0][r]));
  }

  __syncthreads();  // B3: V^T visible for cross-wave reads

  // ---- Node = (W · V)/64 -> t2 own stripe ----
  {
    bf8_t wh0 = ld8(t2, arow, k0a), wh1 = ld8(t2, arow, k0b);
    f32x4 nacc[4];
#pragma unroll
    for (int i = 0; i < 4; ++i) nacc[i] = f32x4{0.f, 0.f, 0.f, 0.f};
#pragma unroll
    for (int n0 = 0; n0 < 4; ++n0) {
      const int brow = n0 * 16 + lr;
      nacc[n0] = mfma16(wh0, ld8(t1, brow, k0a), nacc[n0]);
      nacc[n0] = mfma16(wh1, ld8(t1, brow, k0b), nacc[n0]);
    }
#pragma unroll
    for (int n0 = 0; n0 < 4; ++n0)
#pragma unroll
      for (int r = 0; r < 4; ++r)
        stE(t2, 16 * w + 4 * lg + r, n0 * 16 + lr, nacc[n0][r] * 0.015625f);
  }

  // ---- H = leaky_relu(Node · Wf1^T) -> t2 own stripe ----
  {
    bf8_t nh0 = ld8(t2, arow, k0a), nh1 = ld8(t2, arow, k0b);
    f32x4 hacc[4];
#pragma unroll
    for (int i = 0; i < 4; ++i) hacc[i] = f32x4{0.f, 0.f, 0.f, 0.f};
#pragma unroll
    for (int n0 = 0; n0 < 4; ++n0) {
      const int col = n0 * 16 + lr;
      hacc[n0] = mfma16(nh0, *(const bf8_t*)(ws + W_F1 + col * 64 + k0a), hacc[n0]);
      hacc[n0] = mfma16(nh1, *(const bf8_t*)(ws + W_F1 + col * 64 + k0b), hacc[n0]);
    }
#pragma unroll
    for (int n0 = 0; n0 < 4; ++n0)
#pragma unroll
      for (int r = 0; r < 4; ++r) {
        const float x = hacc[n0][r];
        stE(t2, 16 * w + 4 * lg + r, n0 * 16 + lr, fmaxf(x, 0.01f * x));
      }
  }

  // ---- policy = softmax16(H · Wf2^T) -> out ----
  {
    bf8_t hh0 = ld8(t2, arow, k0a), hh1 = ld8(t2, arow, k0b);
    f32x4 p = f32x4{0.f, 0.f, 0.f, 0.f};
    p = mfma16(hh0, *(const bf8_t*)(ws + W_F2 + lr * 64 + k0a), p);
    p = mfma16(hh1, *(const bf8_t*)(ws + W_F2 + lr * 64 + k0b), p);

    float* pout = out + (long)b * (NAGENT * NACT);
#pragma unroll
    for (int r = 0; r < 4; ++r) {
      float m = p[r];
#pragma unroll
      for (int msk = 1; msk < 16; msk <<= 1) m = fmaxf(m, __shfl_xor(m, msk));
      float e = __expf(p[r] - m);
      float s = e;
#pragma unroll
      for (int msk = 1; msk < 16; msk <<= 1) s += __shfl_xor(s, msk);
      pout[(16 * w + 4 * lg + r) * 16 + lr] = e / s;
    }
  }
}

extern "C" void kernel_launch(void* const* d_in, const int* in_sizes, int n_in,
                              void* d_out, int out_size, void* d_ws, size_t ws_size,
                              hipStream_t stream) {
  const float* states = (const float*)d_in[0];
  const float* W_emb  = (const float*)d_in[1];
  const float* b_emb  = (const float*)d_in[2];
  const float* W_k    = (const float*)d_in[3];
  const float* W_q    = (const float*)d_in[4];
  const float* W_v    = (const float*)d_in[5];
  const float* W_f1   = (const float*)d_in[6];
  const float* W_f2   = (const float*)d_in[7];
  short* ws  = (short*)d_ws;
  float* out = (float*)d_out;

  hipLaunchKernelGGL(prep_weights, dim3(69), dim3(256), 0, stream,
                     W_emb, W_k, W_q, W_v, W_f1, W_f2, ws);
  hipLaunchKernelGGL(sdpp_kernel, dim3(NBATCH), dim3(256), 0, stream,
                     states, b_emb, ws, out);
}